// Round 16
// baseline (38.590 us; speedup 1.0000x reference)
//
#include <hip/hip_runtime.h>
#include <math.h>

// MVAE forward, round 16 = round 15 skeleton with ONE structural change:
// mu/lv/z computed REDUNDANTLY PER WG (r8-proven math; weights via gll16
// into LDS, batch 2; a2 via one cload4) -> bar4 removed (7 barriers), and
// z becomes LDS-local for S4 (no z cload RT, no shuffle build).
// Minor: WGs 64..127 skip polls 1-2 (they produce/consume nothing gated);
// s_sleep(1). All other mechanisms verbatim r14/r15 (MAGIC phase slots,
// WG0 self-cleanup, cstore/cload sc1 discipline, gll16 staging batches).

#define NWG    128
#define NWAVES (NWG * 4)
#define BLOCK  256
#define MAGIC  0x7E57A11E
#define NPHASE 7

__device__ __align__(128) float g_a0[256];
__device__ __align__(128) float g_a1[256];
__device__ __align__(128) float g_a2[256];
__device__ __align__(128) float g_g0[256];
__device__ __align__(128) float g_g1[256];
__device__ __align__(128) float g_g2[256];
__device__ __align__(128) float g_gates[32];
__device__ __align__(128) float g_h0[1536];
__device__ __align__(128) float g_h1[1536];
__device__ __align__(128) float g_h2[1536];
__device__ __align__(128) float g_oute[384];

struct P {
  const float *prev, *curr, *eps;
  const float *ew0,*eb0,*ew1,*eb1,*ew2,*eb2;
  const float *muw,*mub,*lvw,*lvb;
  const float *gw0,*gb0,*gw1,*gb1,*gw2,*gb2,*gw3,*gb3;
  const float *xw0,*xb0,*xw1,*xb1,*xw2,*xb2,*xw3,*xb3;
  float* out;
};

__device__ __forceinline__ float cload(const float* a) {
  int v = __hip_atomic_load((const int*)a, __ATOMIC_RELAXED,
                            __HIP_MEMORY_SCOPE_AGENT);
  return __int_as_float(v);
}
__device__ __forceinline__ void cstore(float* a, float v) {
  __hip_atomic_store((int*)a, __float_as_int(v), __ATOMIC_RELAXED,
                     __HIP_MEMORY_SCOPE_AGENT);
}
__device__ __forceinline__ float4 cload4(const float* a) {
  float4 r;
  r.x = cload(a + 0); r.y = cload(a + 1);
  r.z = cload(a + 2); r.w = cload(a + 3);
  return r;
}
__device__ __forceinline__ void gll16(const void* g, void* l) {
  __builtin_amdgcn_global_load_lds((const __attribute__((address_space(1))) void*)g,
                                   (__attribute__((address_space(3))) void*)l,
                                   16, 0, 0);
}
__device__ __forceinline__ void gll4(const void* g, void* l) {
  __builtin_amdgcn_global_load_lds((const __attribute__((address_space(1))) void*)g,
                                   (__attribute__((address_space(3))) void*)l,
                                   4, 0, 0);
}
__device__ __forceinline__ float wred(float v) {
#pragma unroll
  for (int m = 32; m; m >>= 1) v += __shfl_xor(v, m, 64);
  return v;
}
__device__ __forceinline__ float elu(float x) { return x > 0.f ? x : expm1f(x); }
__device__ __forceinline__ float dot4(float4 a, float4 b) {
  return a.x*b.x + a.y*b.y + a.z*b.z + a.w*b.w;
}

// ---- phase-slot flags: slot(ph, wg) at flags[((ph-1)*NWG + wg)*16] ----
__device__ __forceinline__ int* slotp(int* flags, int ph, int wg) {
  return &flags[((ph - 1) * NWG + wg) * 16];
}
__device__ __forceinline__ void bar_arrive(int* flags, int ph) {
  __syncthreads();                 // vmcnt(0) drain: sc1 stores ack'd at MALL
  if (threadIdx.x == 0)
    __hip_atomic_store(slotp(flags, ph, blockIdx.x), MAGIC,
                       __ATOMIC_RELAXED, __HIP_MEMORY_SCOPE_AGENT);
}
__device__ __forceinline__ void bar_poll(int* flags, int ph, int nprod) {
  if (threadIdx.x < 64) {
    const int l = threadIdx.x;
    for (;;) {
      bool ok = true;
      for (int w = l; w < nprod; w += 64)
        ok &= (__hip_atomic_load(slotp(flags, ph, w),
                                 __ATOMIC_RELAXED, __HIP_MEMORY_SCOPE_AGENT)
               == MAGIC);
      if (ok) break;
      __builtin_amdgcn_s_sleep(1);
    }
  }
  __syncthreads();
}

__global__ __launch_bounds__(BLOCK, 1) void mvae_main(P p, int* flags) {
  const int tid  = threadIdx.x;
  const int lane = tid & 63;
  const int wvin = tid >> 6;
  const int Wv   = blockIdx.x * 4 + wvin;    // 0..511
  const bool early = (blockIdx.x < 64);      // produces in S0..S2

  __shared__ __align__(16) float s_w1[4][256];
  __shared__ __align__(16) float s_w2[4][256];
  __shared__ __align__(16) float s_wml[4][16 * 256];  // mu/lv rows, 64KB
  __shared__ __align__(16) float s_w4[4][4][96];
  __shared__ __align__(16) float s_w5[4][4][288];
  __shared__ __align__(16) float s_w6[4][4][288];
  __shared__ __align__(16) float s_w7[4][288];
  __shared__ float s_ml[64];
  __shared__ float s_z[32];
  __shared__ float s_o[384];
  __shared__ float s_gg[8];

  // ===== staging batch 1 (entry): enc1 rows =====
  if (Wv < 256)
    gll16(p.ew1 + Wv * 256 + lane * 4, s_w1[wvin]);

  // ===== S0: enc0 (plain coalesced loads) =====
  if (Wv < 256) {
    const float* wr = p.ew0 + Wv * 124;
    float wa = wr[lane];
    float wb = (lane < 60) ? wr[64 + lane] : 0.f;
    float xa = (lane < 62) ? p.prev[lane] : p.curr[lane - 62];
    float xb = (lane < 60) ? p.curr[lane + 2] : 0.f;
    float s = wred(wa * xa + wb * xb);
    if (!lane) cstore(&g_a0[Wv], elu(s + p.eb0[Wv]));
  }
  bar_arrive(flags, 1);
  // ===== staging batch 2: enc2 rows + mu/lv rows (16/wave) =====
  if (Wv < 256)
    gll16(p.ew2 + Wv * 256 + lane * 4, s_w2[wvin]);
#pragma unroll
  for (int i = 0; i < 16; ++i) {
    int row = wvin * 16 + i;                 // 0..31 mu, 32..63 lv
    const float* src = (row < 32) ? p.muw + row * 256
                                  : p.lvw + (row - 32) * 256;
    gll16(src + lane * 4, s_wml[wvin] + i * 256);
  }
  if (early) bar_poll(flags, 1, 64);

  // ===== S1: enc1 =====
  if (Wv < 256) {
    float4 w = *(const float4*)(s_w1[wvin] + 4 * lane);
    float4 x = cload4(g_a0 + 4 * lane);
    float s = wred(dot4(w, x));
    if (!lane) cstore(&g_a1[Wv], elu(s + p.eb1[Wv]));
  }
  bar_arrive(flags, 2);
  // ===== staging batch 3: S4 + S5 rows =====
#pragma unroll
  for (int k = 0; k < 4; ++k) {
    int r = Wv + NWAVES * k;
    if (r < 1792) {
      const float* src = (r < 256) ? p.gw0 + r * 94 : p.xw0 + (size_t)(r - 256) * 94;
      float* dst = s_w4[wvin][k];
      if (lane < 23)       gll16(src + lane * 4, dst);
      else if (lane == 23) { gll4(src + 92, dst + 69);    // -> float 92
                             gll4(src + 93, dst + 70); }  // -> float 93
    }
  }
#pragma unroll
  for (int k = 0; k < 4; ++k) {
    int r = Wv + NWAVES * k;
    if (r < 1792) {
      float* dst = s_w5[wvin][k];
      if (r < 256) gll16(p.gw1 + r * 256 + lane * 4, dst);
      else {
        const float* src = p.xw1 + (size_t)(r - 256) * 288;
        gll16(src + lane * 4, dst);
        if (lane < 8) gll16(src + 256 + lane * 4, dst + 256);
      }
    }
  }
  if (early) bar_poll(flags, 2, 64);

  // ===== S2: enc2 =====
  if (Wv < 256) {
    float4 w = *(const float4*)(s_w2[wvin] + 4 * lane);
    float4 x = cload4(g_a1 + 4 * lane);
    float s = wred(dot4(w, x));
    if (!lane) cstore(&g_a2[Wv], elu(s + p.eb2[Wv]));
  }
  bar_arrive(flags, 3);
  // ===== staging batch 4: S6 + S7 rows =====
#pragma unroll
  for (int k = 0; k < 4; ++k) {
    int r = Wv + NWAVES * k;
    if (r < 1792) {
      float* dst = s_w6[wvin][k];
      if (r < 256) gll16(p.gw2 + r * 256 + lane * 4, dst);
      else {
        const float* src = p.xw2 + (size_t)(r - 256) * 288;
        gll16(src + lane * 4, dst);
        if (lane < 8) gll16(src + 256 + lane * 4, dst + 256);
      }
    }
  }
  if (Wv < 6) {
    gll16(p.gw3 + Wv * 256 + lane * 4, s_w7[wvin]);
  } else if (Wv < 378) {
    const float* src = p.xw3 + (size_t)(Wv - 6) * 288;
    float* dst = s_w7[wvin];
    gll16(src + lane * 4, dst);
    if (lane < 8) gll16(src + 256 + lane * 4, dst + 256);
  }
  bar_poll(flags, 3, 64);   // everyone needs a2 now

  // ===== S3': mu/lv/z REDUNDANT per WG (LDS weights, one a2 cload) =====
  {
    float4 x = cload4(g_a2 + 4 * lane);
#pragma unroll
    for (int i = 0; i < 16; ++i) {
      float4 w = *(const float4*)(s_wml[wvin] + i * 256 + 4 * lane);
      float s = wred(dot4(w, x));
      int row = wvin * 16 + i;
      if (!lane)
        s_ml[row] = s + ((row < 32) ? p.mub[row] : p.lvb[row - 32]);
    }
  }
  __syncthreads();
  if (tid < 32) {
    float mu = s_ml[tid], lv = s_ml[32 + tid];
    s_z[tid] = mu + p.eps[tid] * expf(0.5f * lv);
    if (blockIdx.x == 0) { p.out[62 + tid] = mu; p.out[94 + tid] = lv; }
  }
  __syncthreads();

  // per-lane S4 inputs (z from LDS; prev cached read-only)
  float prevA = (lane >= 32 && lane < 94) ? p.prev[lane - 32] : 0.f;
  float prevB = (lane < 30) ? p.prev[32 + lane] : 0.f;
  float xa94 = (lane < 32) ? s_z[lane] : prevA;

  // ===== S4: gate0 + expert h0 (94-dots, LDS weights) =====
#pragma unroll
  for (int k = 0; k < 4; ++k) {
    int r = Wv + NWAVES * k;
    if (r < 1792) {
      const float* wrow = s_w4[wvin][k];
      float wa = wrow[lane];
      float wb = (lane < 30) ? wrow[64 + lane] : 0.f;
      float s = wred(wa * xa94 + wb * prevB);
      if (!lane) {
        if (r < 256) cstore(&g_g0[r], elu(s + p.gb0[r]));
        else         cstore(&g_h0[r - 256], elu(s + p.xb0[r - 256]));
      }
    }
  }
  bar_arrive(flags, 4);
  bar_poll(flags, 4, NWG);

  // ===== S5: gate1 + expert h1 =====
#pragma unroll
  for (int k = 0; k < 4; ++k) {
    int r = Wv + NWAVES * k;
    if (r < 1792) {
      const float* wrow = s_w5[wvin][k];
      float4 w = *(const float4*)(wrow + 4 * lane);
      if (r < 256) {
        float4 x = cload4(g_g0 + 4 * lane);
        float s = wred(dot4(w, x));
        if (!lane) cstore(&g_g1[r], elu(s + p.gb1[r]));
      } else {
        int q = r - 256, e = q >> 8;
        const float* hsrc = g_h0 + e * 256;
        float4 xh;
        if (lane < 8) xh = *(const float4*)(s_z + 4 * lane);
        else          xh = cload4(hsrc + 4 * lane - 32);
        float s = dot4(w, xh);
        if (lane < 32) s += wrow[256 + lane] * cload(hsrc + 224 + lane);
        s = wred(s);
        if (!lane) cstore(&g_h1[q], elu(s + p.xb1[q]));
      }
    }
  }
  bar_arrive(flags, 5);
  bar_poll(flags, 5, NWG);

  // ===== S6: gate2 + expert h2 =====
#pragma unroll
  for (int k = 0; k < 4; ++k) {
    int r = Wv + NWAVES * k;
    if (r < 1792) {
      const float* wrow = s_w6[wvin][k];
      float4 w = *(const float4*)(wrow + 4 * lane);
      if (r < 256) {
        float4 x = cload4(g_g1 + 4 * lane);
        float s = wred(dot4(w, x));
        if (!lane) cstore(&g_g2[r], elu(s + p.gb2[r]));
      } else {
        int q = r - 256, e = q >> 8;
        const float* hsrc = g_h1 + e * 256;
        float4 xh;
        if (lane < 8) xh = *(const float4*)(s_z + 4 * lane);
        else          xh = cload4(hsrc + 4 * lane - 32);
        float s = dot4(w, xh);
        if (lane < 32) s += wrow[256 + lane] * cload(hsrc + 224 + lane);
        s = wred(s);
        if (!lane) cstore(&g_h2[q], elu(s + p.xb2[q]));
      }
    }
  }
  bar_arrive(flags, 6);
  bar_poll(flags, 6, NWG);

  // ===== S7: gate3 logits (6) + out_e (372) =====
  if (Wv < 6) {
    float4 w = *(const float4*)(s_w7[wvin] + 4 * lane);
    float4 x = cload4(g_g2 + 4 * lane);
    float s = wred(dot4(w, x));
    if (!lane) cstore(&g_gates[Wv], s + p.gb3[Wv]);    // raw logits
  } else if (Wv < 378) {
    int q = Wv - 6, e = q / 62;
    const float* wrow = s_w7[wvin];
    float4 w = *(const float4*)(wrow + 4 * lane);
    const float* hsrc = g_h2 + e * 256;
    float4 xh;
    if (lane < 8) xh = *(const float4*)(s_z + 4 * lane);
    else          xh = cload4(hsrc + 4 * lane - 32);
    float s = dot4(w, xh);
    if (lane < 32) s += wrow[256 + lane] * cload(hsrc + 224 + lane);
    s = wred(s);
    if (!lane) cstore(&g_oute[q], s + p.xb3[q]);
  }

  // ===== bar7: all arrive; only WG0 polls (decode) =====
  bar_arrive(flags, 7);
  if (blockIdx.x != 0) return;
  bar_poll(flags, 7, NWG);

  // ===== S8: decode (WG0) =====
  s_o[tid] = cload(&g_oute[tid]);
  if (tid < 116) s_o[tid + 256] = cload(&g_oute[tid + 256]);
  if (tid < 6)   s_gg[tid] = cload(&g_gates[tid]);
  __syncthreads();
  if (tid < 62) {
    float s = 0.f;
#pragma unroll
    for (int e = 0; e < 6; ++e) s += s_o[e * 62 + tid] * s_gg[e];
    p.out[tid] = s;
  }

  // ===== cleanup: zero all flag slots for the next call =====
  // Safe: WG0 passed bar7's poll => every WG arrived bar7 => every WG passed
  // all earlier polls and never polls again this call.
  for (int idx = tid; idx < NPHASE * NWG; idx += BLOCK)
    __hip_atomic_store(&flags[idx * 16], 0,
                       __ATOMIC_RELAXED, __HIP_MEMORY_SCOPE_AGENT);
}

extern "C" void kernel_launch(void* const* d_in, const int* in_sizes, int n_in,
                              void* d_out, int out_size, void* d_ws, size_t ws_size,
                              hipStream_t stream) {
  (void)in_sizes; (void)n_in; (void)out_size; (void)ws_size;
  const float* const* in = (const float* const*)d_in;
  P p;
  p.prev = in[0];  p.curr = in[1];  p.eps = in[2];
  p.ew0 = in[3];   p.eb0 = in[4];   p.ew1 = in[5];  p.eb1 = in[6];
  p.ew2 = in[7];   p.eb2 = in[8];
  p.muw = in[9];   p.mub = in[10];  p.lvw = in[11]; p.lvb = in[12];
  p.gw0 = in[13];  p.gb0 = in[14];  p.gw1 = in[15]; p.gb1 = in[16];
  p.gw2 = in[17];  p.gb2 = in[18];  p.gw3 = in[19]; p.gb3 = in[20];
  p.xw0 = in[21];  p.xb0 = in[22];  p.xw1 = in[23]; p.xb1 = in[24];
  p.xw2 = in[25];  p.xb2 = in[26];  p.xw3 = in[27]; p.xb3 = in[28];
  p.out = (float*)d_out;

  int* flags = (int*)d_ws;     // 7 phases x 128 WGs x 64B, self-cleaning
  mvae_main<<<NWG, BLOCK, 0, stream>>>(p, flags);
}

// Round 17
// 32.829 us; speedup vs baseline: 1.1755x; 1.1755x over previous
//
#include <hip/hip_runtime.h>
#include <math.h>

// MVAE forward, round 17 = EXACT REVERT to round 14 (best proven: 32.5us,
// absmax 0.0, no outlier dispatches).
// r15 (batched staging, NWG=128, subset polls) was flat; r16 (redundant
// mu/lv, 64KB/WG staging) regressed −6us and produced a 40ms livelock-ish
// outlier. Post-mortem: the removed hop (~1.5us) was cheaper than the added
// per-CU staging drain (~3us) on the critical path; conditional poll-skips
// are fragile. This topology (row-per-wave, 8 MAGIC-flag barriers, sc1
// cstore/cload, entry gll16 staging) is at its minimum dependent-hop count.

#define NWG   256
#define BLOCK 256
#define MAGIC 0x7E57A11E

__device__ __align__(128) float g_a0[256];
__device__ __align__(128) float g_a1[256];
__device__ __align__(128) float g_a2[256];
__device__ __align__(128) float g_mu[32];
__device__ __align__(128) float g_lv[32];
__device__ __align__(128) float g_g0[256];
__device__ __align__(128) float g_g1[256];
__device__ __align__(128) float g_g2[256];
__device__ __align__(128) float g_gates[32];
__device__ __align__(128) float g_h0[1536];
__device__ __align__(128) float g_h1[1536];
__device__ __align__(128) float g_h2[1536];
__device__ __align__(128) float g_oute[384];

struct P {
  const float *prev, *curr, *eps;
  const float *ew0,*eb0,*ew1,*eb1,*ew2,*eb2;
  const float *muw,*mub,*lvw,*lvb;
  const float *gw0,*gb0,*gw1,*gb1,*gw2,*gb2,*gw3,*gb3;
  const float *xw0,*xb0,*xw1,*xb1,*xw2,*xb2,*xw3,*xb3;
  float* out;
};

__device__ __forceinline__ float cload(const float* a) {
  int v = __hip_atomic_load((const int*)a, __ATOMIC_RELAXED,
                            __HIP_MEMORY_SCOPE_AGENT);
  return __int_as_float(v);
}
__device__ __forceinline__ void cstore(float* a, float v) {
  __hip_atomic_store((int*)a, __float_as_int(v), __ATOMIC_RELAXED,
                     __HIP_MEMORY_SCOPE_AGENT);
}
__device__ __forceinline__ float4 cload4(const float* a) {
  float4 r;
  r.x = cload(a + 0); r.y = cload(a + 1);
  r.z = cload(a + 2); r.w = cload(a + 3);
  return r;
}
__device__ __forceinline__ void gll16(const void* g, void* l) {
  __builtin_amdgcn_global_load_lds((const __attribute__((address_space(1))) void*)g,
                                   (__attribute__((address_space(3))) void*)l,
                                   16, 0, 0);
}
__device__ __forceinline__ void gll4(const void* g, void* l) {
  __builtin_amdgcn_global_load_lds((const __attribute__((address_space(1))) void*)g,
                                   (__attribute__((address_space(3))) void*)l,
                                   4, 0, 0);
}
__device__ __forceinline__ float wred(float v) {
#pragma unroll
  for (int m = 32; m; m >>= 1) v += __shfl_xor(v, m, 64);
  return v;
}
__device__ __forceinline__ float elu(float x) { return x > 0.f ? x : expm1f(x); }
__device__ __forceinline__ float dot4(float4 a, float4 b) {
  return a.x*b.x + a.y*b.y + a.z*b.z + a.w*b.w;
}

// ---- phase-slot flags: slot(ph, wg) at flags[((ph-1)*NWG + wg)*16] ----
__device__ __forceinline__ int* slotp(int* flags, int ph, int wg) {
  return &flags[((ph - 1) * NWG + wg) * 16];
}
__device__ __forceinline__ void bar_arrive(int* flags, int ph) {
  __syncthreads();                 // vmcnt(0) drain: sc1 stores ack'd at MALL
  if (threadIdx.x == 0)
    __hip_atomic_store(slotp(flags, ph, blockIdx.x), MAGIC,
                       __ATOMIC_RELAXED, __HIP_MEMORY_SCOPE_AGENT);
}
__device__ __forceinline__ void bar_poll(int* flags, int ph) {
  if (threadIdx.x < 64) {
    const int l = threadIdx.x;
    for (;;) {
      int v0 = __hip_atomic_load(slotp(flags, ph, l),       __ATOMIC_RELAXED, __HIP_MEMORY_SCOPE_AGENT);
      int v1 = __hip_atomic_load(slotp(flags, ph, l +  64), __ATOMIC_RELAXED, __HIP_MEMORY_SCOPE_AGENT);
      int v2 = __hip_atomic_load(slotp(flags, ph, l + 128), __ATOMIC_RELAXED, __HIP_MEMORY_SCOPE_AGENT);
      int v3 = __hip_atomic_load(slotp(flags, ph, l + 192), __ATOMIC_RELAXED, __HIP_MEMORY_SCOPE_AGENT);
      if (v0 == MAGIC && v1 == MAGIC && v2 == MAGIC && v3 == MAGIC) break;
      __builtin_amdgcn_s_sleep(2);
    }
  }
  __syncthreads();
}
__device__ __forceinline__ void gridbar(int* flags, int ph) {
  bar_arrive(flags, ph);
  bar_poll(flags, ph);
}

__global__ __launch_bounds__(BLOCK, 1) void mvae_main(P p, int* flags) {
  const int tid  = threadIdx.x;
  const int lane = tid & 63;
  const int wvin = tid >> 6;
  const int Wv   = blockIdx.x * 4 + wvin;    // 0..1023

  __shared__ __align__(16) float s_w1[4][256];
  __shared__ __align__(16) float s_w2[4][256];
  __shared__ __align__(16) float s_w3[4][256];
  __shared__ __align__(16) float s_w4[4][2][96];
  __shared__ __align__(16) float s_w5[4][2][288];
  __shared__ __align__(16) float s_w6[4][2][288];
  __shared__ __align__(16) float s_w7[4][288];
  __shared__ float s_o[384];
  __shared__ float s_gg[8];

  // ================= ENTRY STAGING: per-wave weight rows -> LDS ===========
  if (Wv < 256) {
    gll16(p.ew1 + Wv * 256 + lane * 4, s_w1[wvin]);
    gll16(p.ew2 + Wv * 256 + lane * 4, s_w2[wvin]);
  }
  if (Wv < 64) {
    const float* src = (Wv < 32) ? p.muw + Wv * 256 : p.lvw + (Wv - 32) * 256;
    gll16(src + lane * 4, s_w3[wvin]);
  }
#pragma unroll
  for (int k = 0; k < 2; ++k) {            // S4: rows Wv+1024k, 94 floats
    int r = Wv + 1024 * k;
    if (r < 1792) {
      const float* src = (r < 256) ? p.gw0 + r * 94 : p.xw0 + (size_t)(r - 256) * 94;
      float* dst = s_w4[wvin][k];
      if (lane < 23)       gll16(src + lane * 4, dst);
      else if (lane == 23) { gll4(src + 92, dst + 69);    // -> float 92
                             gll4(src + 93, dst + 70); }  // -> float 93
    }
  }
#pragma unroll
  for (int k = 0; k < 2; ++k) {            // S5
    int r = Wv + 1024 * k;
    if (r < 1792) {
      float* dst = s_w5[wvin][k];
      if (r < 256) gll16(p.gw1 + r * 256 + lane * 4, dst);
      else {
        const float* src = p.xw1 + (size_t)(r - 256) * 288;
        gll16(src + lane * 4, dst);
        if (lane < 8) gll16(src + 256 + lane * 4, dst + 256);
      }
    }
  }
#pragma unroll
  for (int k = 0; k < 2; ++k) {            // S6
    int r = Wv + 1024 * k;
    if (r < 1792) {
      float* dst = s_w6[wvin][k];
      if (r < 256) gll16(p.gw2 + r * 256 + lane * 4, dst);
      else {
        const float* src = p.xw2 + (size_t)(r - 256) * 288;
        gll16(src + lane * 4, dst);
        if (lane < 8) gll16(src + 256 + lane * 4, dst + 256);
      }
    }
  }
  if (Wv < 6) {                            // S7
    gll16(p.gw3 + Wv * 256 + lane * 4, s_w7[wvin]);
  } else if (Wv < 378) {
    const float* src = p.xw3 + (size_t)(Wv - 6) * 288;
    float* dst = s_w7[wvin];
    gll16(src + lane * 4, dst);
    if (lane < 8) gll16(src + 256 + lane * 4, dst + 256);
  }

  // ===== S0: enc0 (plain loads; staging streams concurrently) =====
  if (Wv < 256) {
    const float* wr = p.ew0 + Wv * 124;
    float wa = wr[lane];
    float wb = (lane < 60) ? wr[64 + lane] : 0.f;
    float xa = (lane < 62) ? p.prev[lane] : p.curr[lane - 62];
    float xb = (lane < 60) ? p.curr[lane + 2] : 0.f;
    float s = wred(wa * xa + wb * xb);
    if (!lane) cstore(&g_a0[Wv], elu(s + p.eb0[Wv]));
  }
  gridbar(flags, 1);   // arrive's syncthreads drains staging too

  // ===== S1: enc1 (weights from LDS) =====
  if (Wv < 256) {
    float4 w = *(const float4*)(s_w1[wvin] + 4 * lane);
    float4 x = cload4(g_a0 + 4 * lane);
    float s = wred(dot4(w, x));
    if (!lane) cstore(&g_a1[Wv], elu(s + p.eb1[Wv]));
  }
  gridbar(flags, 2);

  // ===== S2: enc2 =====
  if (Wv < 256) {
    float4 w = *(const float4*)(s_w2[wvin] + 4 * lane);
    float4 x = cload4(g_a1 + 4 * lane);
    float s = wred(dot4(w, x));
    if (!lane) cstore(&g_a2[Wv], elu(s + p.eb2[Wv]));
  }
  gridbar(flags, 3);

  // ===== S3: mu / logvar (waves 0..63) =====
  if (Wv < 64) {
    float4 w = *(const float4*)(s_w3[wvin] + 4 * lane);
    float4 x = cload4(g_a2 + 4 * lane);
    float s = wred(dot4(w, x));
    if (!lane) {
      if (Wv < 32) { float v = s + p.mub[Wv]; cstore(&g_mu[Wv], v); p.out[62 + Wv] = v; }
      else { int r = Wv - 32; float v = s + p.lvb[r]; cstore(&g_lv[r], v); p.out[94 + r] = v; }
    }
  }
  gridbar(flags, 4);

  // ===== z per wave (sc1 mu/lv; z4 via shuffles) =====
  float zs = 0.f;
  if (lane < 32)
    zs = cload(&g_mu[lane]) + p.eps[lane] * expf(0.5f * cload(&g_lv[lane]));
  float4 z4;
  z4.x = __shfl(zs, (4 * lane + 0) & 63, 64);
  z4.y = __shfl(zs, (4 * lane + 1) & 63, 64);
  z4.z = __shfl(zs, (4 * lane + 2) & 63, 64);
  z4.w = __shfl(zs, (4 * lane + 3) & 63, 64);
  float prevA = (lane >= 32 && lane < 94) ? p.prev[lane - 32] : 0.f;
  float prevB = (lane < 30) ? p.prev[32 + lane] : 0.f;
  float xa94 = (lane < 32) ? zs : prevA;

  // ===== S4: gate0 + expert h0 (rows of len 94; 2/wave, LDS weights) =====
#pragma unroll
  for (int k = 0; k < 2; ++k) {
    int r = Wv + 1024 * k;
    if (r < 1792) {
      const float* wrow = s_w4[wvin][k];
      float wa = wrow[lane];
      float wb = (lane < 30) ? wrow[64 + lane] : 0.f;
      float s = wred(wa * xa94 + wb * prevB);
      if (!lane) {
        if (r < 256) cstore(&g_g0[r], elu(s + p.gb0[r]));
        else         cstore(&g_h0[r - 256], elu(s + p.xb0[r - 256]));
      }
    }
  }
  gridbar(flags, 5);

  // ===== S5: gate1 + expert h1 =====
#pragma unroll
  for (int k = 0; k < 2; ++k) {
    int r = Wv + 1024 * k;
    if (r < 1792) {
      const float* wrow = s_w5[wvin][k];
      float4 w = *(const float4*)(wrow + 4 * lane);
      if (r < 256) {
        float4 x = cload4(g_g0 + 4 * lane);
        float s = wred(dot4(w, x));
        if (!lane) cstore(&g_g1[r], elu(s + p.gb1[r]));
      } else {
        int q = r - 256, e = q >> 8;
        const float* hsrc = g_h0 + e * 256;
        float4 xh = z4;
        if (lane >= 8) xh = cload4(hsrc + 4 * lane - 32);
        float s = dot4(w, xh);
        if (lane < 32) s += wrow[256 + lane] * cload(hsrc + 224 + lane);
        s = wred(s);
        if (!lane) cstore(&g_h1[q], elu(s + p.xb1[q]));
      }
    }
  }
  gridbar(flags, 6);

  // ===== S6: gate2 + expert h2 =====
#pragma unroll
  for (int k = 0; k < 2; ++k) {
    int r = Wv + 1024 * k;
    if (r < 1792) {
      const float* wrow = s_w6[wvin][k];
      float4 w = *(const float4*)(wrow + 4 * lane);
      if (r < 256) {
        float4 x = cload4(g_g1 + 4 * lane);
        float s = wred(dot4(w, x));
        if (!lane) cstore(&g_g2[r], elu(s + p.gb2[r]));
      } else {
        int q = r - 256, e = q >> 8;
        const float* hsrc = g_h1 + e * 256;
        float4 xh = z4;
        if (lane >= 8) xh = cload4(hsrc + 4 * lane - 32);
        float s = dot4(w, xh);
        if (lane < 32) s += wrow[256 + lane] * cload(hsrc + 224 + lane);
        s = wred(s);
        if (!lane) cstore(&g_h2[q], elu(s + p.xb2[q]));
      }
    }
  }
  gridbar(flags, 7);

  // ===== S7: gate3 logits (6) + out_e (372) =====
  if (Wv < 6) {
    float4 w = *(const float4*)(s_w7[wvin] + 4 * lane);
    float4 x = cload4(g_g2 + 4 * lane);
    float s = wred(dot4(w, x));
    if (!lane) cstore(&g_gates[Wv], s + p.gb3[Wv]);    // raw logits
  } else if (Wv < 378) {
    int q = Wv - 6, e = q / 62;
    const float* wrow = s_w7[wvin];
    float4 w = *(const float4*)(wrow + 4 * lane);
    const float* hsrc = g_h2 + e * 256;
    float4 xh = z4;
    if (lane >= 8) xh = cload4(hsrc + 4 * lane - 32);
    float s = dot4(w, xh);
    if (lane < 32) s += wrow[256 + lane] * cload(hsrc + 224 + lane);
    s = wred(s);
    if (!lane) cstore(&g_oute[q], s + p.xb3[q]);
  }

  // ===== bar8: all arrive; only WG0 polls (decode) =====
  bar_arrive(flags, 8);
  if (blockIdx.x != 0) return;
  bar_poll(flags, 8);

  // ===== S8: decode (WG0) =====
  s_o[tid] = cload(&g_oute[tid]);
  if (tid < 116) s_o[tid + 256] = cload(&g_oute[tid + 256]);
  if (tid < 6)   s_gg[tid] = cload(&g_gates[tid]);
  __syncthreads();
  if (tid < 62) {
    float s = 0.f;
#pragma unroll
    for (int e = 0; e < 6; ++e) s += s_o[e * 62 + tid] * s_gg[e];
    p.out[tid] = s;
  }

  // ===== cleanup: zero all flag slots for the next call =====
  // Safe: WG0 passed bar8's poll => every WG arrived bar8 => every WG passed
  // all earlier polls and never polls again this call.
#pragma unroll
  for (int ph = 1; ph <= 8; ++ph)
    __hip_atomic_store(slotp(flags, ph, tid), 0,
                       __ATOMIC_RELAXED, __HIP_MEMORY_SCOPE_AGENT);
}

extern "C" void kernel_launch(void* const* d_in, const int* in_sizes, int n_in,
                              void* d_out, int out_size, void* d_ws, size_t ws_size,
                              hipStream_t stream) {
  (void)in_sizes; (void)n_in; (void)out_size; (void)ws_size;
  const float* const* in = (const float* const*)d_in;
  P p;
  p.prev = in[0];  p.curr = in[1];  p.eps = in[2];
  p.ew0 = in[3];   p.eb0 = in[4];   p.ew1 = in[5];  p.eb1 = in[6];
  p.ew2 = in[7];   p.eb2 = in[8];
  p.muw = in[9];   p.mub = in[10];  p.lvw = in[11]; p.lvb = in[12];
  p.gw0 = in[13];  p.gb0 = in[14];  p.gw1 = in[15]; p.gb1 = in[16];
  p.gw2 = in[17];  p.gb2 = in[18];  p.gw3 = in[19]; p.gb3 = in[20];
  p.xw0 = in[21];  p.xb0 = in[22];  p.xw1 = in[23]; p.xb1 = in[24];
  p.xw2 = in[25];  p.xb2 = in[26];  p.xw3 = in[27]; p.xb3 = in[28];
  p.out = (float*)d_out;

  int* flags = (int*)d_ws;     // 8 phases x 256 WGs x 64B = 128KB, self-cleaning
  mvae_main<<<NWG, BLOCK, 0, stream>>>(p, flags);
}